// Round 7
// baseline (264.599 us; speedup 1.0000x reference)
//
#include <hip/hip_runtime.h>

#define N_NODES 100000
#define N_EDGES 1600000
#define CAP 48      // deg~Poisson(16); P(deg>=48)*N ~ 3e-6 -> no drops
#define NBUCK 256   // dst-range buckets
#define NPB 391     // nodes per bucket = ceil(100000/256)
#define SCAP 8192   // bucket segment capacity (mean 6250, sigma 79 -> +24 sigma)
#define EPB 2048    // edges per bin block (r7: was 4096; 783 blocks -> 3 waves/SIMD)
#define NBIN ((N_EDGES + EPB - 1) / EPB)     // 782

typedef unsigned int uint;
typedef unsigned short ushort;

__device__ __forceinline__ void fma4(float4& c, float s, const float4& w) {
    c.x += s * w.x; c.y += s * w.y; c.z += s * w.z; c.w += s * w.w;
}

__device__ __forceinline__ ushort bf16r(float f) {   // fp32 -> bf16 RNE
    union { float f; uint u; } v; v.f = f;
    return (ushort)((v.u + 0x7fffu + ((v.u >> 16) & 1u)) >> 16);
}

// ---------------- fp32 GEMM block: 128 rows x 64 cols, 8x4 thread tile --------
// Round-5 lesson: 8 consecutive rows/thread -> wave's rgs read rows 8*stride
// apart == 0 mod 32 banks -> unavoidable 4-way (8-way at 8 rgs) LDS conflict.
// Round-7 fix: ROW-INTERLEAVED tile: thread owns rows rg + 16*r. The wave's 4
// rgs then read rows 1 apart (36 words = 4 banks) -> disjoint bank spans
// [b..b+3][b+4..b+7][b+8..b+11][b+12..b+15], 16-lane broadcast per addr: free.
struct alignas(16) GemmSmem {
    float Xs[128][36];   // stride 36: 16B-aligned rows
    float Ws[32][64];
};

template <typename OutT>
__device__ __forceinline__ void gemm64_block(GemmSmem& sm, int bid,
                                             const float* __restrict__ X,
                                             const float* __restrict__ W,
                                             OutT* __restrict__ H, int n) {
    const int tid  = threadIdx.x;
    const int row0 = bid * 128;
    const int rg   = tid >> 4;          // 0..15: rows rg, rg+16, ..., rg+112
    const int cg   = tid & 15;          // col group: cg*4

    float4 acc0[8];
#pragma unroll
    for (int r = 0; r < 8; r++) acc0[r] = make_float4(0.f, 0.f, 0.f, 0.f);

    const int lr = tid >> 1;
    const int lh = tid & 1;
    int grow = row0 + lr; if (grow > n - 1) grow = n - 1;   // clamp tail reads
    const float* gx_base = X + (size_t)grow * 128 + lh * 16;

    for (int k0 = 0; k0 < 128; k0 += 32) {
        const float* gx = gx_base + k0;
#pragma unroll
        for (int i = 0; i < 4; i++)
            *(float4*)&sm.Xs[lr][lh * 16 + 4 * i] = *(const float4*)(gx + 4 * i);
        const float4* gw = (const float4*)(W + (size_t)k0 * 64);
        float4* sw = (float4*)&sm.Ws[0][0];
#pragma unroll
        for (int i = 0; i < 2; i++) sw[tid + 256 * i] = gw[tid + 256 * i];
        __syncthreads();

#pragma unroll
        for (int kk = 0; kk < 32; kk += 4) {
            float4 w00 = *(const float4*)&sm.Ws[kk + 0][cg * 4];
            float4 w01 = *(const float4*)&sm.Ws[kk + 1][cg * 4];
            float4 w02 = *(const float4*)&sm.Ws[kk + 2][cg * 4];
            float4 w03 = *(const float4*)&sm.Ws[kk + 3][cg * 4];
#pragma unroll
            for (int r = 0; r < 8; r++) {
                float4 a = *(const float4*)&sm.Xs[rg + 16 * r][kk];
                fma4(acc0[r], a.x, w00);
                fma4(acc0[r], a.y, w01);
                fma4(acc0[r], a.z, w02);
                fma4(acc0[r], a.w, w03);
            }
        }
        __syncthreads();
    }

#pragma unroll
    for (int r = 0; r < 8; r++) {
        int row = row0 + rg + 16 * r;
        if (row < n) {
            if constexpr (sizeof(OutT) == 2) {   // bf16 epilogue, node-major
                ushort4 o0 = make_ushort4(bf16r(acc0[r].x), bf16r(acc0[r].y),
                                          bf16r(acc0[r].z), bf16r(acc0[r].w));
                *(ushort4*)&H[(size_t)row * 64 + cg * 4] = o0;
            } else {
                *(float4*)&H[(size_t)row * 64 + cg * 4] = *(float4*)&acc0[r];
            }
        }
    }
}

// ---------------- Pass A + weight collapse (fused) ----------------
// Blocks 0..NBIN-1: edge binning. Block NBIN: Wc = W1 @ (W2 @ W3).
// Round-6: LDS bucket-sort (phase-1 slot + exclusive scan) -> coalesced
// writeout runs. Round-7: EPB 4096->2048 — the 392-block grid was only
// 1.5 waves/SIMD (occupancy-starved); 783 blocks restores latency hiding.
union BinWcSmem {
    struct {
        int ecnt[NBUCK];
        int base[NBUCK];
        int lofs[NBUCK];
        uint2 estage[EPB];   // 16 KB bucket-sorted staging
    } b;                     // 19.8 KB
    GemmSmem g;              // 26.6 KB
};

__global__ void __launch_bounds__(256) bin_wc(const int* __restrict__ src,
                                              const int* __restrict__ dst,
                                              int* __restrict__ gcur,
                                              uint2* __restrict__ seg, int E,
                                              const float* __restrict__ W1,
                                              const float* __restrict__ W2,
                                              const float* __restrict__ W3,
                                              float* __restrict__ W23,
                                              float* __restrict__ Wc) {
    __shared__ BinWcSmem sh;
    if (blockIdx.x == gridDim.x - 1) {      // weight-collapse block
        gemm64_block<float>(sh.g, 0, W2, W3, W23, 128);
        __syncthreads();                     // W23 global writes visible in-block
        gemm64_block<float>(sh.g, 0, W1, W23, Wc, 128);
        return;
    }
    const int t = threadIdx.x;
    sh.b.ecnt[t] = 0;                        // t spans exactly NBUCK
    __syncthreads();
    const int e0 = blockIdx.x * EPB;
    uint sreg[EPB / 256];
    int  dreg[EPB / 256];
    int  slreg[EPB / 256];
    // phase 1: LDS histogram; returned value IS this edge's in-bucket slot
#pragma unroll
    for (int k = 0; k < EPB / 256; k++) {
        int i = e0 + k * 256 + t;
        if (i < E) {
            int d = dst[i];
            sreg[k] = (uint)src[i];
            dreg[k] = d;
            slreg[k] = atomicAdd(&sh.b.ecnt[d / NPB], 1);
        }
    }
    __syncthreads();
    // phase 2a: one global reserving atomic per non-empty bucket
    const int c = sh.b.ecnt[t];
    sh.b.base[t] = (c > 0) ? atomicAdd(&gcur[t], c) : 0;
    // phase 2b: exclusive scan of ecnt -> lofs (Hillis-Steele over 256)
    sh.b.lofs[t] = c;
    __syncthreads();
#pragma unroll
    for (int off = 1; off < NBUCK; off <<= 1) {
        int u = (t >= off) ? sh.b.lofs[t - off] : 0;
        __syncthreads();
        sh.b.lofs[t] += u;
        __syncthreads();
    }
    const int excl = sh.b.lofs[t] - c;       // inclusive -> exclusive
    __syncthreads();
    sh.b.lofs[t] = excl;
    __syncthreads();
    // phase 3a: stage edges bucket-sorted in LDS
#pragma unroll
    for (int k = 0; k < EPB / 256; k++) {
        int i = e0 + k * 256 + t;
        if (i < E) {
            int b = dreg[k] / NPB;
            sh.b.estage[sh.b.lofs[b] + slreg[k]] =
                make_uint2(sreg[k], (uint)dreg[k]);
        }
    }
    __syncthreads();
    // phase 3b: coalesced write-out; consecutive i = same-bucket runs (~8)
    const int total = min(E - e0, EPB);
    for (int i = t; i < total; i += 256) {
        uint2 e = sh.b.estage[i];
        int b = (int)e.y / NPB;
        int s = sh.b.base[b] + (i - sh.b.lofs[b]);
        if (s < SCAP) seg[(size_t)b * SCAP + s] = e;
    }
}

// ---------------- Pass B + main GEMM (fused, heterogeneous blocks) ----------------
// CSR build (global-scatter/latency-bound, light LDS) overlapped with
// Y = X @ Wc (LDS/VALU-bound) — pipe-disjoint pairing (round-1 proven).
union CsrGemmSmem {
    int lc[NPB];
    GemmSmem g;
};

__global__ void __launch_bounds__(256, 3) csr_gemm(const int* __restrict__ gcur,
                                                   const uint2* __restrict__ seg,
                                                   int* __restrict__ col,
                                                   int* __restrict__ cnt,
                                                   const float* __restrict__ X,
                                                   const float* __restrict__ Wc,
                                                   ushort* __restrict__ Y, int n) {
    __shared__ CsrGemmSmem sh;
    if (blockIdx.x < NBUCK) {
        const int b = blockIdx.x;
        const int t = threadIdx.x;
        for (int i = t; i < NPB; i += 256) sh.lc[i] = 0;
        __syncthreads();
        int m = gcur[b]; if (m > SCAP) m = SCAP;
        const uint2* sg = seg + (size_t)b * SCAP;
        const int node0 = b * NPB;
        for (int i = t; i < m; i += 256) {
            uint2 e = sg[i];
            int d = (int)e.y;
            int slot = atomicAdd(&sh.lc[d - node0], 1);
            if (slot < CAP) col[(size_t)d * CAP + slot] = (int)e.x;
        }
        __syncthreads();
        for (int i = t; i < NPB; i += 256) {
            int node = node0 + i;
            if (node < n) cnt[node] = (sh.lc[i] > CAP) ? CAP : sh.lc[i];
        }
    } else {
        gemm64_block<ushort>(sh.g, blockIdx.x - NBUCK, X, Wc, Y, n);
    }
}

// ---------------- Aggregation, width 64, bf16 table [N][64] ----------------
// 8 lanes per node; lane owns a uint4 (8 dims) -> one coalesced 128 B
// (exactly one cacheline) gather per edge. Round-2 lesson: no dim-split.
__device__ __forceinline__ float2 bf2f(uint u) {
    union { uint u; float f; } a, b;
    a.u = u << 16; b.u = u & 0xffff0000u;
    return make_float2(a.f, b.f);
}

template <bool FINAL>
__global__ void __launch_bounds__(256) agg64(const uint4* __restrict__ T_in,
                                             const int* __restrict__ cnt,
                                             const int* __restrict__ col,
                                             void* __restrict__ T_out, int n) {
    int gid  = blockIdx.x * blockDim.x + threadIdx.x;
    int node = gid >> 3;
    int lane = gid & 7;                  // owns dims [8*lane, 8*lane+8)
    if (node >= n) return;
    int m = cnt[node]; if (m > CAP) m = CAP;
    const int* cb = col + (size_t)node * CAP;
    const uint4* tb = T_in + lane;
    float4 accA = make_float4(0.f, 0.f, 0.f, 0.f);
    float4 accB = make_float4(0.f, 0.f, 0.f, 0.f);
    int j = 0;
    for (; j + 8 <= m; j += 8) {
        int4 c0 = *(const int4*)&cb[j];
        int4 c1 = *(const int4*)&cb[j + 4];
        uint4 u0 = tb[(size_t)c0.x * 8];
        uint4 u1 = tb[(size_t)c0.y * 8];
        uint4 u2 = tb[(size_t)c0.z * 8];
        uint4 u3 = tb[(size_t)c0.w * 8];
        uint4 u4 = tb[(size_t)c1.x * 8];
        uint4 u5 = tb[(size_t)c1.y * 8];
        uint4 u6 = tb[(size_t)c1.z * 8];
        uint4 u7 = tb[(size_t)c1.w * 8];
        float2 p0 = bf2f(u0.x), p1 = bf2f(u1.x), p2 = bf2f(u2.x), p3 = bf2f(u3.x);
        float2 p4 = bf2f(u4.x), p5 = bf2f(u5.x), p6 = bf2f(u6.x), p7 = bf2f(u7.x);
        accA.x += ((p0.x + p1.x) + (p2.x + p3.x)) + ((p4.x + p5.x) + (p6.x + p7.x));
        accA.y += ((p0.y + p1.y) + (p2.y + p3.y)) + ((p4.y + p5.y) + (p6.y + p7.y));
        float2 q0 = bf2f(u0.y), q1 = bf2f(u1.y), q2 = bf2f(u2.y), q3 = bf2f(u3.y);
        float2 q4 = bf2f(u4.y), q5 = bf2f(u5.y), q6 = bf2f(u6.y), q7 = bf2f(u7.y);
        accA.z += ((q0.x + q1.x) + (q2.x + q3.x)) + ((q4.x + q5.x) + (q6.x + q7.x));
        accA.w += ((q0.y + q1.y) + (q2.y + q3.y)) + ((q4.y + q5.y) + (q6.y + q7.y));
        float2 r0 = bf2f(u0.z), r1 = bf2f(u1.z), r2 = bf2f(u2.z), r3 = bf2f(u3.z);
        float2 r4 = bf2f(u4.z), r5 = bf2f(u5.z), r6 = bf2f(u6.z), r7 = bf2f(u7.z);
        accB.x += ((r0.x + r1.x) + (r2.x + r3.x)) + ((r4.x + r5.x) + (r6.x + r7.x));
        accB.y += ((r0.y + r1.y) + (r2.y + r3.y)) + ((r4.y + r5.y) + (r6.y + r7.y));
        float2 s0 = bf2f(u0.w), s1 = bf2f(u1.w), s2 = bf2f(u2.w), s3 = bf2f(u3.w);
        float2 s4 = bf2f(u4.w), s5 = bf2f(u5.w), s6 = bf2f(u6.w), s7 = bf2f(u7.w);
        accB.z += ((s0.x + s1.x) + (s2.x + s3.x)) + ((s4.x + s5.x) + (s6.x + s7.x));
        accB.w += ((s0.y + s1.y) + (s2.y + s3.y)) + ((s4.y + s5.y) + (s6.y + s7.y));
    }
    for (; j + 4 <= m; j += 4) {
        int4 c0 = *(const int4*)&cb[j];
        uint4 u0 = tb[(size_t)c0.x * 8];
        uint4 u1 = tb[(size_t)c0.y * 8];
        uint4 u2 = tb[(size_t)c0.z * 8];
        uint4 u3 = tb[(size_t)c0.w * 8];
        float2 p0 = bf2f(u0.x), p1 = bf2f(u1.x), p2 = bf2f(u2.x), p3 = bf2f(u3.x);
        accA.x += (p0.x + p1.x) + (p2.x + p3.x);
        accA.y += (p0.y + p1.y) + (p2.y + p3.y);
        float2 q0 = bf2f(u0.y), q1 = bf2f(u1.y), q2 = bf2f(u2.y), q3 = bf2f(u3.y);
        accA.z += (q0.x + q1.x) + (q2.x + q3.x);
        accA.w += (q0.y + q1.y) + (q2.y + q3.y);
        float2 r0 = bf2f(u0.z), r1 = bf2f(u1.z), r2 = bf2f(u2.z), r3 = bf2f(u3.z);
        accB.x += (r0.x + r1.x) + (r2.x + r3.x);
        accB.y += (r0.y + r1.y) + (r2.y + r3.y);
        float2 s0 = bf2f(u0.w), s1 = bf2f(u1.w), s2 = bf2f(u2.w), s3 = bf2f(u3.w);
        accB.z += (s0.x + s1.x) + (s2.x + s3.x);
        accB.w += (s0.y + s1.y) + (s2.y + s3.y);
    }
    for (; j < m; j++) {
        uint4 u = tb[(size_t)cb[j] * 8];
        float2 p = bf2f(u.x), q = bf2f(u.y), r = bf2f(u.z), s = bf2f(u.w);
        accA.x += p.x; accA.y += p.y; accA.z += q.x; accA.w += q.y;
        accB.x += r.x; accB.y += r.y; accB.z += s.x; accB.w += s.y;
    }
    if (FINAL) {
        ((float4*)T_out)[(size_t)node * 16 + lane * 2]     = accA;
        ((float4*)T_out)[(size_t)node * 16 + lane * 2 + 1] = accB;
    } else {
        uint4 o;
        o.x = (uint)bf16r(accA.x) | ((uint)bf16r(accA.y) << 16);
        o.y = (uint)bf16r(accA.z) | ((uint)bf16r(accA.w) << 16);
        o.z = (uint)bf16r(accB.x) | ((uint)bf16r(accB.y) << 16);
        o.w = (uint)bf16r(accB.z) | ((uint)bf16r(accB.w) << 16);
        ((uint4*)T_out)[(size_t)node * 8 + lane] = o;
    }
}

// ---------------- launch ----------------
// ALGEBRAIC COLLAPSE: out = A(A(A X W1)W2)W3 = A^3 . X . (W1 W2 W3)
// Pipeline: [bin(EPB=2048, LDS-sorted writeout) + wc]
//           [CSR || 8x4 row-interleaved GEMM][agg x3].

static inline size_t align_up(size_t x, size_t a) { return (x + a - 1) & ~(a - 1); }

extern "C" void kernel_launch(void* const* d_in, const int* in_sizes, int n_in,
                              void* d_out, int out_size, void* d_ws, size_t ws_size,
                              hipStream_t stream) {
    const float* x  = (const float*)d_in[0];
    const int*   ei = (const int*)d_in[1];   // [2, E]
    const float* W1 = (const float*)d_in[2];
    const float* W2 = (const float*)d_in[3];
    const float* W3 = (const float*)d_in[4];
    float* out = (float*)d_out;

    const int N = N_NODES;
    const int E = N_EDGES;
    const int* src = ei;
    const int* dst = ei + E;

    // workspace carve-up (~63 MB)
    char* p = (char*)d_ws;
    int*    gcur = (int*)p;   p += align_up((size_t)NBUCK * 4, 256);
    int*    cnt  = (int*)p;   p += align_up((size_t)N * 4, 256);
    uint2*  seg  = (uint2*)p; p += align_up((size_t)NBUCK * SCAP * 8, 256);  // 16.8 MB
    int*    col  = (int*)p;   p += align_up((size_t)N * CAP * 4, 256);       // 19.2 MB
    float*  W23  = (float*)p; p += align_up((size_t)128 * 64 * 4, 256);
    float*  Wc   = (float*)p; p += align_up((size_t)128 * 64 * 4, 256);
    ushort* Y    = (ushort*)p; p += align_up((size_t)N * 64 * 2, 256);  // bf16 node table
    ushort* Za   = (ushort*)p; p += align_up((size_t)N * 64 * 2, 256);  // bf16 ping-pong

    hipMemsetAsync(gcur, 0, (size_t)NBUCK * 4, stream);

    // ---- Pass A: bin edges; last block computes Wc = W1 @ (W2 @ W3) ----
    bin_wc<<<NBIN + 1, 256, 0, stream>>>(src, dst, gcur, seg, E,
                                         W1, W2, W3, W23, Wc);

    // ---- Pass B (blocks 0..255) overlapped with Y = X @ Wc (blocks 256..) ----
    const int gemm_blocks = (N + 127) / 128;             // 782
    csr_gemm<<<NBUCK + gemm_blocks, 256, 0, stream>>>(gcur, seg, col, cnt,
                                                      x, Wc, Y, N);

    // ---- out = A^3 Y ----
    const int agg_blocks = (N * 8 + 255) / 256;          // 3125
    agg64<false><<<agg_blocks, 256, 0, stream>>>((const uint4*)Y,  cnt, col, Za, N);
    agg64<false><<<agg_blocks, 256, 0, stream>>>((const uint4*)Za, cnt, col, Y,  N);
    agg64<true ><<<agg_blocks, 256, 0, stream>>>((const uint4*)Y,  cnt, col, out, N);
}

// Round 8
// 251.109 us; speedup vs baseline: 1.0537x; 1.0537x over previous
//
#include <hip/hip_runtime.h>

#define N_NODES 100000
#define N_EDGES 1600000
#define CAP 48      // deg~Poisson(16); P(deg>=48)*N ~ 3e-6 -> no drops
#define NBUCK 256   // dst-range buckets
#define NPB 391     // nodes per bucket = ceil(100000/256)
#define SCAP 8192   // bucket segment capacity
#define NREP 4      // gcur replicas; quarter cap 2048 = mean 1562 + 12 sigma
#define SCAP4 (SCAP / NREP)
#define EPB 4096    // edges per bin block (r7 lesson: 2048 grew the atomic chain)
#define NBIN ((N_EDGES + EPB - 1) / EPB)     // 391

typedef unsigned int uint;
typedef unsigned short ushort;

__device__ __forceinline__ void fma4(float4& c, float s, const float4& w) {
    c.x += s * w.x; c.y += s * w.y; c.z += s * w.z; c.w += s * w.w;
}

__device__ __forceinline__ ushort bf16r(float f) {   // fp32 -> bf16 RNE
    union { float f; uint u; } v; v.f = f;
    return (ushort)((v.u + 0x7fffu + ((v.u >> 16) & 1u)) >> 16);
}

// ---------------- fp32 GEMM block: 128 rows x 64 cols, 8x4 thread tile --------
// Round-5 lesson: 8 consecutive rows/thread -> wave's rgs read rows 8*stride
// apart == 0 mod 32 banks -> unavoidable 4-way LDS conflict (8-way at 8 rgs).
// Round-7 fix (kept): ROW-INTERLEAVED tile: thread owns rows rg + 16*r. The
// wave's 4 rgs read adjacent rows (36 words = 4 banks apart) -> disjoint bank
// spans, 16-lane broadcast per address: conflict-free.
struct alignas(16) GemmSmem {
    float Xs[128][36];   // stride 36: 16B-aligned rows
    float Ws[32][64];
};

template <typename OutT>
__device__ __forceinline__ void gemm64_block(GemmSmem& sm, int bid,
                                             const float* __restrict__ X,
                                             const float* __restrict__ W,
                                             OutT* __restrict__ H, int n) {
    const int tid  = threadIdx.x;
    const int row0 = bid * 128;
    const int rg   = tid >> 4;          // 0..15: rows rg, rg+16, ..., rg+112
    const int cg   = tid & 15;          // col group: cg*4

    float4 acc0[8];
#pragma unroll
    for (int r = 0; r < 8; r++) acc0[r] = make_float4(0.f, 0.f, 0.f, 0.f);

    const int lr = tid >> 1;
    const int lh = tid & 1;
    int grow = row0 + lr; if (grow > n - 1) grow = n - 1;   // clamp tail reads
    const float* gx_base = X + (size_t)grow * 128 + lh * 16;

    for (int k0 = 0; k0 < 128; k0 += 32) {
        const float* gx = gx_base + k0;
#pragma unroll
        for (int i = 0; i < 4; i++)
            *(float4*)&sm.Xs[lr][lh * 16 + 4 * i] = *(const float4*)(gx + 4 * i);
        const float4* gw = (const float4*)(W + (size_t)k0 * 64);
        float4* sw = (float4*)&sm.Ws[0][0];
#pragma unroll
        for (int i = 0; i < 2; i++) sw[tid + 256 * i] = gw[tid + 256 * i];
        __syncthreads();

#pragma unroll
        for (int kk = 0; kk < 32; kk += 4) {
            float4 w00 = *(const float4*)&sm.Ws[kk + 0][cg * 4];
            float4 w01 = *(const float4*)&sm.Ws[kk + 1][cg * 4];
            float4 w02 = *(const float4*)&sm.Ws[kk + 2][cg * 4];
            float4 w03 = *(const float4*)&sm.Ws[kk + 3][cg * 4];
#pragma unroll
            for (int r = 0; r < 8; r++) {
                float4 a = *(const float4*)&sm.Xs[rg + 16 * r][kk];
                fma4(acc0[r], a.x, w00);
                fma4(acc0[r], a.y, w01);
                fma4(acc0[r], a.z, w02);
                fma4(acc0[r], a.w, w03);
            }
        }
        __syncthreads();
    }

#pragma unroll
    for (int r = 0; r < 8; r++) {
        int row = row0 + rg + 16 * r;
        if (row < n) {
            if constexpr (sizeof(OutT) == 2) {   // bf16 epilogue, node-major
                ushort4 o0 = make_ushort4(bf16r(acc0[r].x), bf16r(acc0[r].y),
                                          bf16r(acc0[r].z), bf16r(acc0[r].w));
                *(ushort4*)&H[(size_t)row * 64 + cg * 4] = o0;
            } else {
                *(float4*)&H[(size_t)row * 64 + cg * 4] = *(float4*)&acc0[r];
            }
        }
    }
}

// ---------------- Pass A + weight collapse (fused) ----------------
// Blocks 0..NBIN-1: edge binning (LDS hist -> in-reg slots -> LDS bucket-sort
// -> coalesced writeout). Block NBIN: Wc = W1 @ (W2 @ W3).
// Round-8 change: the per-bucket reserving atomic serialized 391 same-word
// returning L2 atomics per bucket (the invariant ~40 us stall across all bin
// variants; r7's block-count scaling confirmed). NREP=4 replica counters cut
// each chain to ~98; seg buckets split into 4 quarters.
union BinWcSmem {
    struct {
        int ecnt[NBUCK];
        int base[NBUCK];
        int lofs[NBUCK];
        uint2 estage[EPB];   // 32 KB bucket-sorted staging
    } b;                     // 35.8 KB
    GemmSmem g;              // 26.6 KB
};

__global__ void __launch_bounds__(256) bin_wc(const int* __restrict__ src,
                                              const int* __restrict__ dst,
                                              int* __restrict__ gcur,
                                              uint2* __restrict__ seg, int E,
                                              const float* __restrict__ W1,
                                              const float* __restrict__ W2,
                                              const float* __restrict__ W3,
                                              float* __restrict__ W23,
                                              float* __restrict__ Wc) {
    __shared__ BinWcSmem sh;
    if (blockIdx.x == gridDim.x - 1) {      // weight-collapse block
        gemm64_block<float>(sh.g, 0, W2, W3, W23, 128);
        __syncthreads();                     // W23 global writes visible in-block
        gemm64_block<float>(sh.g, 0, W1, W23, Wc, 128);
        return;
    }
    const int t = threadIdx.x;
    sh.b.ecnt[t] = 0;                        // t spans exactly NBUCK
    __syncthreads();
    const int e0 = blockIdx.x * EPB;
    const int rep = blockIdx.x & (NREP - 1); // replica counter set for this block
    uint sreg[EPB / 256];
    int  dreg[EPB / 256];
    int  slreg[EPB / 256];
    // phase 1: LDS histogram; returned value IS this edge's in-bucket slot
#pragma unroll
    for (int k = 0; k < EPB / 256; k++) {
        int i = e0 + k * 256 + t;
        if (i < E) {
            int d = dst[i];
            sreg[k] = (uint)src[i];
            dreg[k] = d;
            slreg[k] = atomicAdd(&sh.b.ecnt[d / NPB], 1);
        }
    }
    __syncthreads();
    // phase 2a: one reserving atomic per non-empty bucket, on this block's
    // replica word (chain length ~NBIN/NREP instead of NBIN)
    const int c = sh.b.ecnt[t];
    sh.b.base[t] = (c > 0) ? atomicAdd(&gcur[rep * NBUCK + t], c) : 0;
    // phase 2b: exclusive scan of ecnt -> lofs (Hillis-Steele over 256)
    sh.b.lofs[t] = c;
    __syncthreads();
#pragma unroll
    for (int off = 1; off < NBUCK; off <<= 1) {
        int u = (t >= off) ? sh.b.lofs[t - off] : 0;
        __syncthreads();
        sh.b.lofs[t] += u;
        __syncthreads();
    }
    const int excl = sh.b.lofs[t] - c;       // inclusive -> exclusive
    __syncthreads();
    sh.b.lofs[t] = excl;
    __syncthreads();
    // phase 3a: stage edges bucket-sorted in LDS
#pragma unroll
    for (int k = 0; k < EPB / 256; k++) {
        int i = e0 + k * 256 + t;
        if (i < E) {
            int b = dreg[k] / NPB;
            sh.b.estage[sh.b.lofs[b] + slreg[k]] =
                make_uint2(sreg[k], (uint)dreg[k]);
        }
    }
    __syncthreads();
    // phase 3b: coalesced write-out into this block's replica quarter
    const int total = min(E - e0, EPB);
    for (int i = t; i < total; i += 256) {
        uint2 e = sh.b.estage[i];
        int b = (int)e.y / NPB;
        int s = sh.b.base[b] + (i - sh.b.lofs[b]);
        if (s < SCAP4)
            seg[(size_t)b * SCAP + rep * SCAP4 + s] = e;
    }
}

// ---------------- Pass B + main GEMM (fused, heterogeneous blocks) ----------------
// CSR build (global-scatter/latency-bound, light LDS) overlapped with
// Y = X @ Wc (LDS/VALU-bound) — pipe-disjoint pairing (round-1 proven).
union CsrGemmSmem {
    int lc[NPB];
    GemmSmem g;
};

__global__ void __launch_bounds__(256, 3) csr_gemm(const int* __restrict__ gcur,
                                                   const uint2* __restrict__ seg,
                                                   int* __restrict__ col,
                                                   int* __restrict__ cnt,
                                                   const float* __restrict__ X,
                                                   const float* __restrict__ Wc,
                                                   ushort* __restrict__ Y, int n) {
    __shared__ CsrGemmSmem sh;
    if (blockIdx.x < NBUCK) {
        const int b = blockIdx.x;
        const int t = threadIdx.x;
        for (int i = t; i < NPB; i += 256) sh.lc[i] = 0;
        __syncthreads();
        const int node0 = b * NPB;
#pragma unroll
        for (int q = 0; q < NREP; q++) {
            int m = gcur[q * NBUCK + b]; if (m > SCAP4) m = SCAP4;
            const uint2* sg = seg + (size_t)b * SCAP + q * SCAP4;
            for (int i = t; i < m; i += 256) {
                uint2 e = sg[i];
                int d = (int)e.y;
                int slot = atomicAdd(&sh.lc[d - node0], 1);
                if (slot < CAP) col[(size_t)d * CAP + slot] = (int)e.x;
            }
        }
        __syncthreads();
        for (int i = t; i < NPB; i += 256) {
            int node = node0 + i;
            if (node < n) cnt[node] = (sh.lc[i] > CAP) ? CAP : sh.lc[i];
        }
    } else {
        gemm64_block<ushort>(sh.g, blockIdx.x - NBUCK, X, Wc, Y, n);
    }
}

// ---------------- Aggregation, width 64, bf16 table [N][64] ----------------
// 8 lanes per node; lane owns a uint4 (8 dims) -> one coalesced 128 B
// (exactly one cacheline) gather per edge. Round-2 lesson: no dim-split.
// FETCH ~85 MB/pass = compulsory per-XCD working set (random graph): at floor.
__device__ __forceinline__ float2 bf2f(uint u) {
    union { uint u; float f; } a, b;
    a.u = u << 16; b.u = u & 0xffff0000u;
    return make_float2(a.f, b.f);
}

template <bool FINAL>
__global__ void __launch_bounds__(256) agg64(const uint4* __restrict__ T_in,
                                             const int* __restrict__ cnt,
                                             const int* __restrict__ col,
                                             void* __restrict__ T_out, int n) {
    int gid  = blockIdx.x * blockDim.x + threadIdx.x;
    int node = gid >> 3;
    int lane = gid & 7;                  // owns dims [8*lane, 8*lane+8)
    if (node >= n) return;
    int m = cnt[node]; if (m > CAP) m = CAP;
    const int* cb = col + (size_t)node * CAP;
    const uint4* tb = T_in + lane;
    float4 accA = make_float4(0.f, 0.f, 0.f, 0.f);
    float4 accB = make_float4(0.f, 0.f, 0.f, 0.f);
    int j = 0;
    for (; j + 8 <= m; j += 8) {
        int4 c0 = *(const int4*)&cb[j];
        int4 c1 = *(const int4*)&cb[j + 4];
        uint4 u0 = tb[(size_t)c0.x * 8];
        uint4 u1 = tb[(size_t)c0.y * 8];
        uint4 u2 = tb[(size_t)c0.z * 8];
        uint4 u3 = tb[(size_t)c0.w * 8];
        uint4 u4 = tb[(size_t)c1.x * 8];
        uint4 u5 = tb[(size_t)c1.y * 8];
        uint4 u6 = tb[(size_t)c1.z * 8];
        uint4 u7 = tb[(size_t)c1.w * 8];
        float2 p0 = bf2f(u0.x), p1 = bf2f(u1.x), p2 = bf2f(u2.x), p3 = bf2f(u3.x);
        float2 p4 = bf2f(u4.x), p5 = bf2f(u5.x), p6 = bf2f(u6.x), p7 = bf2f(u7.x);
        accA.x += ((p0.x + p1.x) + (p2.x + p3.x)) + ((p4.x + p5.x) + (p6.x + p7.x));
        accA.y += ((p0.y + p1.y) + (p2.y + p3.y)) + ((p4.y + p5.y) + (p6.y + p7.y));
        float2 q0 = bf2f(u0.y), q1 = bf2f(u1.y), q2 = bf2f(u2.y), q3 = bf2f(u3.y);
        float2 q4 = bf2f(u4.y), q5 = bf2f(u5.y), q6 = bf2f(u6.y), q7 = bf2f(u7.y);
        accA.z += ((q0.x + q1.x) + (q2.x + q3.x)) + ((q4.x + q5.x) + (q6.x + q7.x));
        accA.w += ((q0.y + q1.y) + (q2.y + q3.y)) + ((q4.y + q5.y) + (q6.y + q7.y));
        float2 r0 = bf2f(u0.z), r1 = bf2f(u1.z), r2 = bf2f(u2.z), r3 = bf2f(u3.z);
        float2 r4 = bf2f(u4.z), r5 = bf2f(u5.z), r6 = bf2f(u6.z), r7 = bf2f(u7.z);
        accB.x += ((r0.x + r1.x) + (r2.x + r3.x)) + ((r4.x + r5.x) + (r6.x + r7.x));
        accB.y += ((r0.y + r1.y) + (r2.y + r3.y)) + ((r4.y + r5.y) + (r6.y + r7.y));
        float2 s0 = bf2f(u0.w), s1 = bf2f(u1.w), s2 = bf2f(u2.w), s3 = bf2f(u3.w);
        float2 s4 = bf2f(u4.w), s5 = bf2f(u5.w), s6 = bf2f(u6.w), s7 = bf2f(u7.w);
        accB.z += ((s0.x + s1.x) + (s2.x + s3.x)) + ((s4.x + s5.x) + (s6.x + s7.x));
        accB.w += ((s0.y + s1.y) + (s2.y + s3.y)) + ((s4.y + s5.y) + (s6.y + s7.y));
    }
    for (; j + 4 <= m; j += 4) {
        int4 c0 = *(const int4*)&cb[j];
        uint4 u0 = tb[(size_t)c0.x * 8];
        uint4 u1 = tb[(size_t)c0.y * 8];
        uint4 u2 = tb[(size_t)c0.z * 8];
        uint4 u3 = tb[(size_t)c0.w * 8];
        float2 p0 = bf2f(u0.x), p1 = bf2f(u1.x), p2 = bf2f(u2.x), p3 = bf2f(u3.x);
        accA.x += (p0.x + p1.x) + (p2.x + p3.x);
        accA.y += (p0.y + p1.y) + (p2.y + p3.y);
        float2 q0 = bf2f(u0.y), q1 = bf2f(u1.y), q2 = bf2f(u2.y), q3 = bf2f(u3.y);
        accA.z += (q0.x + q1.x) + (q2.x + q3.x);
        accA.w += (q0.y + q1.y) + (q2.y + q3.y);
        float2 r0 = bf2f(u0.z), r1 = bf2f(u1.z), r2 = bf2f(u2.z), r3 = bf2f(u3.z);
        accB.x += (r0.x + r1.x) + (r2.x + r3.x);
        accB.y += (r0.y + r1.y) + (r2.y + r3.y);
        float2 s0 = bf2f(u0.w), s1 = bf2f(u1.w), s2 = bf2f(u2.w), s3 = bf2f(u3.w);
        accB.z += (s0.x + s1.x) + (s2.x + s3.x);
        accB.w += (s0.y + s1.y) + (s2.y + s3.y);
    }
    for (; j < m; j++) {
        uint4 u = tb[(size_t)cb[j] * 8];
        float2 p = bf2f(u.x), q = bf2f(u.y), r = bf2f(u.z), s = bf2f(u.w);
        accA.x += p.x; accA.y += p.y; accA.z += q.x; accA.w += q.y;
        accB.x += r.x; accB.y += r.y; accB.z += s.x; accB.w += s.y;
    }
    if (FINAL) {
        ((float4*)T_out)[(size_t)node * 16 + lane * 2]     = accA;
        ((float4*)T_out)[(size_t)node * 16 + lane * 2 + 1] = accB;
    } else {
        uint4 o;
        o.x = (uint)bf16r(accA.x) | ((uint)bf16r(accA.y) << 16);
        o.y = (uint)bf16r(accA.z) | ((uint)bf16r(accA.w) << 16);
        o.z = (uint)bf16r(accB.x) | ((uint)bf16r(accB.y) << 16);
        o.w = (uint)bf16r(accB.z) | ((uint)bf16r(accB.w) << 16);
        ((uint4*)T_out)[(size_t)node * 8 + lane] = o;
    }
}

// ---------------- launch ----------------
// ALGEBRAIC COLLAPSE: out = A(A(A X W1)W2)W3 = A^3 . X . (W1 W2 W3)
// Pipeline: [bin(EPB=4096, 4-replica reservation, LDS-sorted writeout) + wc]
//           [CSR(4 quarters) || 8x4 row-interleaved GEMM][agg x3].

static inline size_t align_up(size_t x, size_t a) { return (x + a - 1) & ~(a - 1); }

extern "C" void kernel_launch(void* const* d_in, const int* in_sizes, int n_in,
                              void* d_out, int out_size, void* d_ws, size_t ws_size,
                              hipStream_t stream) {
    const float* x  = (const float*)d_in[0];
    const int*   ei = (const int*)d_in[1];   // [2, E]
    const float* W1 = (const float*)d_in[2];
    const float* W2 = (const float*)d_in[3];
    const float* W3 = (const float*)d_in[4];
    float* out = (float*)d_out;

    const int N = N_NODES;
    const int E = N_EDGES;
    const int* src = ei;
    const int* dst = ei + E;

    // workspace carve-up (~63 MB)
    char* p = (char*)d_ws;
    int*    gcur = (int*)p;   p += align_up((size_t)NREP * NBUCK * 4, 256);
    int*    cnt  = (int*)p;   p += align_up((size_t)N * 4, 256);
    uint2*  seg  = (uint2*)p; p += align_up((size_t)NBUCK * SCAP * 8, 256);  // 16.8 MB
    int*    col  = (int*)p;   p += align_up((size_t)N * CAP * 4, 256);       // 19.2 MB
    float*  W23  = (float*)p; p += align_up((size_t)128 * 64 * 4, 256);
    float*  Wc   = (float*)p; p += align_up((size_t)128 * 64 * 4, 256);
    ushort* Y    = (ushort*)p; p += align_up((size_t)N * 64 * 2, 256);  // bf16 node table
    ushort* Za   = (ushort*)p; p += align_up((size_t)N * 64 * 2, 256);  // bf16 ping-pong

    hipMemsetAsync(gcur, 0, (size_t)NREP * NBUCK * 4, stream);

    // ---- Pass A: bin edges; last block computes Wc = W1 @ (W2 @ W3) ----
    bin_wc<<<NBIN + 1, 256, 0, stream>>>(src, dst, gcur, seg, E,
                                         W1, W2, W3, W23, Wc);

    // ---- Pass B (blocks 0..255) overlapped with Y = X @ Wc (blocks 256..) ----
    const int gemm_blocks = (N + 127) / 128;             // 782
    csr_gemm<<<NBUCK + gemm_blocks, 256, 0, stream>>>(gcur, seg, col, cnt,
                                                      x, Wc, Y, N);

    // ---- out = A^3 Y ----
    const int agg_blocks = (N * 8 + 255) / 256;          // 3125
    agg64<false><<<agg_blocks, 256, 0, stream>>>((const uint4*)Y,  cnt, col, Za, N);
    agg64<false><<<agg_blocks, 256, 0, stream>>>((const uint4*)Za, cnt, col, Y,  N);
    agg64<true ><<<agg_blocks, 256, 0, stream>>>((const uint4*)Y,  cnt, col, out, N);
}